// Round 18
// baseline (208.784 us; speedup 1.0000x reference)
//
#include <hip/hip_runtime.h>

#define NEG 0.2f

typedef __attribute__((ext_vector_type(4))) float f32x4;
typedef __attribute__((ext_vector_type(8))) short bf16x8;

// ---------- bf16 pack/unpack (RNE) ----------
__device__ __forceinline__ float blo(unsigned u) { return __uint_as_float(u << 16); }
__device__ __forceinline__ float bhi(unsigned u) { return __uint_as_float(u & 0xffff0000u); }
__device__ __forceinline__ unsigned bpack(float a, float b) {
  unsigned ua = __float_as_uint(a), ub = __float_as_uint(b);
  unsigned ra = (ua + 0x7fffu + ((ua >> 16) & 1u)) >> 16;
  unsigned rb = (ub + 0x7fffu + ((ub >> 16) & 1u)) >> 16;
  return ra | (rb << 16);
}
__device__ __forceinline__ unsigned short b16(float a) {
  unsigned ua = __float_as_uint(a);
  return (unsigned short)((ua + 0x7fffu + ((ua >> 16) & 1u)) >> 16);
}

// 16-lane xor-butterfly reduce via ds_swizzle (pattern immediate, 3 inst/stage).
__device__ __forceinline__ float red16(float t) {
  t += __int_as_float(__builtin_amdgcn_ds_swizzle(__float_as_int(t), 0x041F));  // xor 1
  t += __int_as_float(__builtin_amdgcn_ds_swizzle(__float_as_int(t), 0x081F));  // xor 2
  t += __int_as_float(__builtin_amdgcn_ds_swizzle(__float_as_int(t), 0x101F));  // xor 4
  t += __int_as_float(__builtin_amdgcn_ds_swizzle(__float_as_int(t), 0x201F));  // xor 8
  return t;
}

// ---------- dispatch 1: pack weights -> bf16 B^T AND zero count ----------
__global__ void packW2_k(const float* __restrict__ Wl1, const float* __restrict__ Wr1,
                         const float* __restrict__ Wl2, const float* __restrict__ Wr2,
                         unsigned short* __restrict__ WbT1, unsigned short* __restrict__ WbT2,
                         int* __restrict__ count, int N) {
  int i = blockIdx.x * 256 + threadIdx.x;
  if (i < N) count[i] = 0;
  if (i >= 320 * 128) return;
  int col = i >> 7, k = i & 127;
  if (col < 256) {
    float v = (col < 128) ? Wl1[(size_t)k * 128 + col] : Wr1[(size_t)k * 128 + (col - 128)];
    WbT1[i] = b16(v);
  } else {
    int c2 = col - 256;   // 0..63
    float v = (c2 < 32) ? Wl2[(size_t)k * 32 + c2] : Wr2[(size_t)k * 32 + (c2 - 32)];
    WbT2[(size_t)c2 * 128 + k] = b16(v);
  }
}

// ---------- dispatch 2: convert to int32 + inline width detect + degree histogram ----------
__global__ void convert_k(const void* __restrict__ ei,
                          int* __restrict__ esrc, int* __restrict__ edst,
                          int* __restrict__ count, int E, int Etot, int n_nodes) {
  __shared__ int is64s;
  if (threadIdx.x < 64) {   // wave 0: detect int64 vs int32 (P(false+) ~ (1/N)^64)
    const long long* e64 = (const long long*)ei;
    long long v = e64[threadIdx.x];
    bool ok = (v >= 0 && v < (long long)n_nodes);
    unsigned long long bm = __ballot(ok);
    if (threadIdx.x == 0) is64s = (bm == ~0ull) ? 1 : 0;
  }
  __syncthreads();
  int is64 = is64s;
  int e = blockIdx.x * 256 + threadIdx.x;
  if (e >= Etot) return;
  int src, dst;
  if (e >= E) { src = e - E; dst = e - E; }  // self-loops appended
  else if (is64) {
    const long long* p = (const long long*)ei;
    src = (int)p[e];
    dst = (int)p[(size_t)E + e];
  } else {
    const int* p = (const int*)ei;
    src = p[e];
    dst = p[E + e];
  }
  esrc[e] = src;
  edst[e] = dst;
  atomicAdd(&count[dst], 1);
}

// ---------- dispatch 3: scanA = per-block sums (scan1) || 32-chunk LPT degree hist ----------
__global__ void scanA_k(const int* __restrict__ count, int* __restrict__ bsum,
                        int* __restrict__ hist2d, int N, int nscan, int cs) {
  __shared__ int sh[256];
  if ((int)blockIdx.x < nscan) {
    int i = blockIdx.x * 256 + threadIdx.x;
    sh[threadIdx.x] = (i < N) ? count[i] : 0;
    __syncthreads();
    for (int o = 128; o; o >>= 1) {
      if (threadIdx.x < o) sh[threadIdx.x] += sh[threadIdx.x + o];
      __syncthreads();
    }
    if (threadIdx.x == 0) bsum[blockIdx.x] = sh[0];
  } else {
    int blk = blockIdx.x - nscan;   // 0..31
    sh[threadIdx.x] = 0;
    __syncthreads();
    int hi = min(N, (blk + 1) * cs);
    for (int i = blk * cs + threadIdx.x; i < hi; i += 256) {
      int d = count[i];
      d = d < 255 ? d : 255;
      atomicAdd(&sh[255 - d], 1);   // LDS atomic; bin 0 = highest degree
    }
    __syncthreads();
    hist2d[threadIdx.x * 32 + blk] = sh[threadIdx.x];
  }
}

// ---------- dispatch 4: scanB = top scan of bsum (block 0) || 8192-elem deg scan (block 1) ----------
__global__ void scanB_k(int* __restrict__ bsum, int nb,
                        const int* __restrict__ hist2d, int* __restrict__ base2d) {
  __shared__ int sd[1024];
  int t = threadIdx.x;
  if (blockIdx.x == 0) {
    int v = (t < nb) ? bsum[t] : 0;
    sd[t] = v;
    __syncthreads();
    for (int o = 1; o < 256; o <<= 1) {
      int x = (t >= o) ? sd[t - o] : 0;
      __syncthreads();
      sd[t] += x;
      __syncthreads();
    }
    if (t < nb) bsum[t] = sd[t] - v;
  } else {
    int v[8], s = 0;
#pragma unroll
    for (int k = 0; k < 8; ++k) { v[k] = hist2d[t * 8 + k]; s += v[k]; }
    sd[t] = s;
    __syncthreads();
    for (int o = 1; o < 1024; o <<= 1) {
      int x = (t >= o) ? sd[t - o] : 0;
      __syncthreads();
      sd[t] += x;
      __syncthreads();
    }
    int run = sd[t] - s;
#pragma unroll
    for (int k = 0; k < 8; ++k) { base2d[t * 8 + k] = run; run += v[k]; }
  }
}

// ---------- dispatch 5: scanC = csroff/cursor (scan3) || LPT perm scatter ----------
__global__ void scanC_k(const int* __restrict__ count, const int* __restrict__ bsum,
                        int* __restrict__ csroff, int* __restrict__ cursor,
                        const int* __restrict__ base2d, int* __restrict__ perm,
                        int N, int Etot, int nscan, int cs) {
  __shared__ int sh[256];
  if ((int)blockIdx.x < nscan) {
    int i = blockIdx.x * 256 + threadIdx.x;
    int v = (i < N) ? count[i] : 0;
    sh[threadIdx.x] = v;
    __syncthreads();
    for (int o = 1; o < 256; o <<= 1) {
      int t2 = (threadIdx.x >= o) ? sh[threadIdx.x - o] : 0;
      __syncthreads();
      sh[threadIdx.x] += t2;
      __syncthreads();
    }
    if (i < N) {
      int ex = bsum[blockIdx.x] + sh[threadIdx.x] - v;
      csroff[i] = ex;
      cursor[i] = ex;
    }
    if (i == 0) csroff[N] = Etot;
  } else {
    int blk = blockIdx.x - nscan;   // 0..31
    sh[threadIdx.x] = 0;
    __syncthreads();
    int hi = min(N, (blk + 1) * cs);
    for (int i = blk * cs + threadIdx.x; i < hi; i += 256) {
      int d = count[i];
      d = d < 255 ? d : 255;
      int db = 255 - d;
      int r = atomicAdd(&sh[db], 1);   // intra-bin order arbitrary; outputs unaffected
      perm[base2d[db * 32 + blk] + r] = i;
    }
  }
}

// ---------- dispatch 6: CSR scatter (XCD-partitioned, own dispatch -> own L2) ----------
__global__ void scatter_xcd_k(const int* __restrict__ esrc, const int* __restrict__ edst,
                              int* __restrict__ cursor, int* __restrict__ bucket,
                              int Etot, int rsz, int N, int ce) {
  int r = blockIdx.x & 7, c = blockIdx.x >> 3;
  int lo = r * rsz, hi = min(N, lo + rsz);
  int eend = min(Etot, (c + 1) * ce);
  for (int e = c * ce + threadIdx.x; e < eend; e += 256) {
    int dst = edst[e];
    if (dst >= lo && dst < hi) {
      int pos = atomicAdd(&cursor[dst], 1);
      bucket[pos] = esrc[e];
    }
  }
}

// ---------- GEMM body (device): [xl|xr](bid rows) = X @ WbT ----------
template <int NCOL, int C, int HS, bool PAIRI, bool ABF16>
__device__ __forceinline__ void gemm_body(int bid, const void* __restrict__ Xv,
                                          const unsigned short* __restrict__ WbT,
                                          unsigned* __restrict__ xl_p, unsigned* __restrict__ xr_p,
                                          int nrows) {
  constexpr int NF = NCOL / 16;
  constexpr int NPM = C / 2;
  constexpr int FPM = C / 16;
  constexpr int FPH = HS / 16;
  constexpr int POFF = HS / 32;
  const int wave = threadIdx.x >> 6;
  const int lane = threadIdx.x & 63;
  const int row0 = bid * 64 + wave * 16;
  const int rA = row0 + (lane & 15);
  const int rAc = (rA < nrows) ? rA : (nrows - 1);
  const int kA = (lane >> 4) * 8;
  const int colB = lane & 15;

  f32x4 acc[NF];
#pragma unroll
  for (int f = 0; f < NF; ++f) acc[f] = (f32x4){0.f, 0.f, 0.f, 0.f};

#pragma unroll
  for (int k0 = 0; k0 < 128; k0 += 32) {
    union { unsigned u[4]; uint4 u4; bf16x8 v; } af;
    if (ABF16) {
      const unsigned short* Xb = (const unsigned short*)Xv;
      af.u4 = *(const uint4*)&Xb[(size_t)rAc * 128 + k0 + kA];
    } else {
      const float* X = (const float*)Xv;
      const float* ax = &X[(size_t)rAc * 128 + k0 + kA];
      float4 a0 = *(const float4*)ax;
      float4 a1 = *(const float4*)(ax + 4);
      af.u[0] = bpack(a0.x, a0.y);
      af.u[1] = bpack(a0.z, a0.w);
      af.u[2] = bpack(a1.x, a1.y);
      af.u[3] = bpack(a1.z, a1.w);
    }
#pragma unroll
    for (int nf = 0; nf < NF; ++nf) {
      union { uint4 u4; bf16x8 v; } bf;
      bf.u4 = *(const uint4*)&WbT[(size_t)(nf * 16 + colB) * 128 + k0 + kA];
      acc[nf] = __builtin_amdgcn_mfma_f32_16x16x32_bf16(af.v, bf.v, acc[nf], 0, 0, 0);
    }
  }

#pragma unroll
  for (int mat = 0; mat < 2; ++mat) {
    unsigned* outp = mat ? xr_p : xl_p;
#pragma unroll
    for (int mf = 0; mf < FPM; ++mf) {
      int head = mf / FPH, hf = mf % FPH;
      if (hf >= POFF) continue;
      int f = mat * FPM + mf;
      int pair = hf * 16 + colB;
      int q = PAIRI ? (2 * pair + head) : (head * (HS / 2) + pair);
#pragma unroll
      for (int r = 0; r < 4; ++r) {
        int row = row0 + ((lane >> 4) << 2) + r;
        if (row < nrows) outp[(size_t)row * NPM + q] = bpack(acc[f][r], acc[f + POFF][r]);
      }
    }
  }
}

// ---------- dispatch 7: layer-1 GEMM ----------
__global__ void gemm1_k(const float* __restrict__ x, const unsigned short* __restrict__ WbT1,
                        unsigned* __restrict__ xl1p, unsigned* __restrict__ xr1p, int N) {
  gemm_body<256, 128, 64, true, false>(blockIdx.x, (const void*)x, WbT1, xl1p, xr1p, N);
}

// ---------- dispatch 9: layer-2 GEMM (bf16 A) ----------
__global__ void gemm2_k(const unsigned* __restrict__ h1b, const unsigned short* __restrict__ WbT2,
                        unsigned* __restrict__ xl2p, unsigned* __restrict__ xr2p, int N) {
  gemm_body<64, 32, 32, false, true>(blockIdx.x, (const void*)h1b, WbT2, xl2p, xr2p, N);
}

// ---------- dispatch 8: layer 1 fused (16 lanes/node, LPT perm, depth-3, bf16 out) ----------
__global__ void fused_layer1_k(const unsigned* __restrict__ xl_p, const unsigned* __restrict__ xr_p,
                               const int* __restrict__ off, const int* __restrict__ bucket,
                               const int* __restrict__ perm,
                               const float* __restrict__ att, const float* __restrict__ b,
                               unsigned* __restrict__ h1b, int N) {
  int grp = threadIdx.x >> 4, sub = threadIdx.x & 15;
  int idx = blockIdx.x * 16 + grp;
  if (idx >= N) return;
  int node = perm[idx];
  const int c0 = 2 * sub, c1 = 2 * sub + 1;
  uint4 xr4 = *(const uint4*)&xr_p[(size_t)node * 64 + 4 * sub];
  float xr0 = blo(xr4.x), xr1 = bhi(xr4.x);   // h0: ch c0, c0+32
  float xr2 = blo(xr4.y), xr3 = bhi(xr4.y);   // h1: ch 64+c0, 96+c0
  float xr4f = blo(xr4.z), xr5 = bhi(xr4.z);  // h0: ch c1, c1+32
  float xr6 = blo(xr4.w), xr7 = bhi(xr4.w);   // h1: ch 64+c1, 96+c1
  float at0 = att[c0], at1 = att[c0 + 32], at2 = att[64 + c0], at3 = att[96 + c0];
  float at4 = att[c1], at5 = att[c1 + 32], at6 = att[64 + c1], at7 = att[96 + c1];

  float m0 = -INFINITY, m1 = -INFINITY, s0 = 0.f, s1 = 0.f;
  float o0 = 0.f, o1 = 0.f, o2 = 0.f, o3 = 0.f, o4 = 0.f, o5 = 0.f, o6 = 0.f, o7 = 0.f;
  int j = off[node], jend = off[node + 1];

  auto tpart = [&](uint4 v, float* vv, float& t0, float& t1) {
    vv[0] = blo(v.x); vv[1] = bhi(v.x); vv[2] = blo(v.y); vv[3] = bhi(v.y);
    vv[4] = blo(v.z); vv[5] = bhi(v.z); vv[6] = blo(v.w); vv[7] = bhi(v.w);
    float e0 = vv[0] + xr0;  e0 = fmaxf(e0, NEG * e0);
    float e1 = vv[1] + xr1;  e1 = fmaxf(e1, NEG * e1);
    float e2 = vv[2] + xr2;  e2 = fmaxf(e2, NEG * e2);
    float e3 = vv[3] + xr3;  e3 = fmaxf(e3, NEG * e3);
    float e4 = vv[4] + xr4f; e4 = fmaxf(e4, NEG * e4);
    float e5 = vv[5] + xr5;  e5 = fmaxf(e5, NEG * e5);
    float e6 = vv[6] + xr6;  e6 = fmaxf(e6, NEG * e6);
    float e7 = vv[7] + xr7;  e7 = fmaxf(e7, NEG * e7);
    t0 = fmaf(e0, at0, e1 * at1) + fmaf(e4, at4, e5 * at5);
    t1 = fmaf(e2, at2, e3 * at3) + fmaf(e6, at6, e7 * at7);
  };

  auto LD = [&](int jj, uint4& a, uint4& bq, int& cnt) {
    int i0 = bucket[jj];
    bool two = (jj + 1 < jend);
    int i1 = two ? bucket[jj + 1] : i0;
    a  = *(const uint4*)&xl_p[(size_t)i0 * 64 + 4 * sub];
    bq = *(const uint4*)&xl_p[(size_t)i1 * 64 + 4 * sub];
    cnt = two ? 2 : 1;
  };

  uint4 a0, b0q, a1, b1q, a2, b2q;
  int c0n = 0, c1n = 0, c2n = 0;
  LD(j, a0, b0q, c0n);
  bool h1v = (j + 2 < jend);
  if (h1v) LD(j + 2, a1, b1q, c1n);
  bool h2v = (j + 4 < jend);
  if (h2v) LD(j + 4, a2, b2q, c2n);

  for (;;) {
    bool h3v = (j + 6 < jend);
    uint4 na, nb;
    int ncn = 0;
    if (h3v) LD(j + 6, na, nb, ncn);   // depth-3 prefetch

    float va[8], vb[8], t0a, t1a, t0b, t1b;
    tpart(a0, va, t0a, t1a);
    tpart(b0q, vb, t0b, t1b);
    if (c0n < 2) { t0b = -1e30f; t1b = -1e30f; }

    t0a = red16(t0a); t1a = red16(t1a);
    t0b = red16(t0b); t1b = red16(t1b);

    float tm0 = fmaxf(t0a, t0b), tm1 = fmaxf(t1a, t1b);
    if (__any((tm0 > m0 + 8.f) || (tm1 > m1 + 8.f))) {
      float nm0 = fmaxf(m0, tm0), nm1 = fmaxf(m1, tm1);
      float c0r = __expf(m0 - nm0), c1r = __expf(m1 - nm1);
      s0 *= c0r; s1 *= c1r;
      o0 *= c0r; o1 *= c0r; o4 *= c0r; o5 *= c0r;
      o2 *= c1r; o3 *= c1r; o6 *= c1r; o7 *= c1r;
      m0 = nm0; m1 = nm1;
    }
    float p0a_e = __expf(t0a - m0), p1a_e = __expf(t1a - m1);
    float p0b_e = __expf(t0b - m0), p1b_e = __expf(t1b - m1);
    s0 += p0a_e + p0b_e;
    s1 += p1a_e + p1b_e;
    o0 = fmaf(p0a_e, va[0], fmaf(p0b_e, vb[0], o0));
    o1 = fmaf(p0a_e, va[1], fmaf(p0b_e, vb[1], o1));
    o4 = fmaf(p0a_e, va[4], fmaf(p0b_e, vb[4], o4));
    o5 = fmaf(p0a_e, va[5], fmaf(p0b_e, vb[5], o5));
    o2 = fmaf(p1a_e, va[2], fmaf(p1b_e, vb[2], o2));
    o3 = fmaf(p1a_e, va[3], fmaf(p1b_e, vb[3], o3));
    o6 = fmaf(p1a_e, va[6], fmaf(p1b_e, vb[6], o6));
    o7 = fmaf(p1a_e, va[7], fmaf(p1b_e, vb[7], o7));

    if (!h1v) break;
    a0 = a1; b0q = b1q; c0n = c1n;
    a1 = a2; b1q = b2q; c1n = c2n;
    h1v = h2v;
    if (h3v) { a2 = na; b2q = nb; c2n = ncn; }
    h2v = h3v;
    j += 2;
  }

  float i0 = 1.f / s0, i1 = 1.f / s1;
  auto elu = [](float r) { return r > 0.f ? r : __expf(r) - 1.f; };
  unsigned* row = h1b + (size_t)node * 64;
  float ra, rb;
  ra = elu(fmaf(o0, i0, b[c0]));       rb = elu(fmaf(o4, i0, b[c1]));
  row[sub] = bpack(ra, rb);
  ra = elu(fmaf(o1, i0, b[c0 + 32]));  rb = elu(fmaf(o5, i0, b[c1 + 32]));
  row[16 + sub] = bpack(ra, rb);
  ra = elu(fmaf(o2, i1, b[64 + c0]));  rb = elu(fmaf(o6, i1, b[64 + c1]));
  row[32 + sub] = bpack(ra, rb);
  ra = elu(fmaf(o3, i1, b[96 + c0]));  rb = elu(fmaf(o7, i1, b[96 + c1]));
  row[48 + sub] = bpack(ra, rb);
}

// ---------- dispatch 10: layer 2 fused ----------
__global__ void fused_layer2_k(const unsigned* __restrict__ xl_p, const unsigned* __restrict__ xr_p,
                               const int* __restrict__ off, const int* __restrict__ bucket,
                               const int* __restrict__ perm,
                               const float* __restrict__ att, const float* __restrict__ b,
                               float* __restrict__ out, int N) {
  int idx = blockIdx.x * 16 + (threadIdx.x >> 4);
  int lane = threadIdx.x & 15;
  if (idx >= N) return;
  int node = perm[idx];
  unsigned xru = xr_p[(size_t)node * 16 + lane];
  float xr_a = blo(xru), xr_b = bhi(xru);
  float att_a = att[lane], att_b = att[lane + 16];
  float m = -INFINITY, s = 0.f, oa = 0.f, ob = 0.f;
  int j0 = off[node], jend = off[node + 1];

  auto tpart = [&](unsigned vu, float& va, float& vb) {
    va = blo(vu); vb = bhi(vu);
    float ea = va + xr_a; ea = fmaxf(ea, NEG * ea);
    float eb = vb + xr_b; eb = fmaxf(eb, NEG * eb);
    return fmaf(ea, att_a, eb * att_b);
  };

  auto upd4 = [&](const unsigned* v, int nvalid) {
    float va0, vb0, va1, vb1, va2, vb2, va3, vb3;
    float t0 = tpart(v[0], va0, vb0);
    float t1 = tpart(v[1], va1, vb1);
    float t2 = tpart(v[2], va2, vb2);
    float t3 = tpart(v[3], va3, vb3);
    if (nvalid < 4) {
      if (nvalid <= 1) t1 = -1e30f;
      if (nvalid <= 2) t2 = -1e30f;
      t3 = -1e30f;
    }
    t0 = red16(t0); t1 = red16(t1); t2 = red16(t2); t3 = red16(t3);
    float tm = fmaxf(fmaxf(t0, t1), fmaxf(t2, t3));
    if (__any(tm > m + 8.f)) {
      float nm = fmaxf(m, tm);
      float c = __expf(m - nm);
      s *= c; oa *= c; ob *= c;
      m = nm;
    }
    float p0 = __expf(t0 - m), p1 = __expf(t1 - m);
    float p2 = __expf(t2 - m), p3 = __expf(t3 - m);
    s += (p0 + p1) + (p2 + p3);
    oa = fmaf(p0, va0, fmaf(p1, va1, fmaf(p2, va2, fmaf(p3, va3, oa))));
    ob = fmaf(p0, vb0, fmaf(p1, vb1, fmaf(p2, vb2, fmaf(p3, vb3, ob))));
  };

  unsigned cv[4], nv[4];
  int deg = jend - j0;
#pragma unroll
  for (int k = 0; k < 4; ++k) {
    int idx2 = j0 + ((k < deg) ? k : 0);
    cv[k] = xl_p[(size_t)bucket[idx2] * 16 + lane];
  }
  int j = j0;
  for (;;) {
    int jn = j + 4;
    bool more = jn < jend;
    if (more) {
      int rem = jend - jn;
#pragma unroll
      for (int k = 0; k < 4; ++k) {
        int idx2 = jn + ((k < rem) ? k : 0);
        nv[k] = xl_p[(size_t)bucket[idx2] * 16 + lane];
      }
    }
    int nvalid = jend - j; if (nvalid > 4) nvalid = 4;
    upd4(cv, nvalid);
    if (!more) break;
#pragma unroll
    for (int k = 0; k < 4; ++k) cv[k] = nv[k];
    j = jn;
  }

  float inv = 1.f / s;
  out[(size_t)node * 32 + lane]      = fmaf(oa, inv, b[lane]);
  out[(size_t)node * 32 + 16 + lane] = fmaf(ob, inv, b[lane + 16]);
}

extern "C" void kernel_launch(void* const* d_in, const int* in_sizes, int n_in,
                              void* d_out, int out_size, void* d_ws, size_t ws_size,
                              hipStream_t stream) {
  const float* x    = (const float*)d_in[0];
  const void*  ei   = d_in[1];
  const float* Wl1  = (const float*)d_in[2];
  const float* Wr1  = (const float*)d_in[3];
  const float* att1 = (const float*)d_in[4];
  const float* b1   = (const float*)d_in[5];
  const float* Wl2  = (const float*)d_in[6];
  const float* Wr2  = (const float*)d_in[7];
  const float* att2 = (const float*)d_in[8];
  const float* b2   = (const float*)d_in[9];

  const int N = in_sizes[0] / 128;
  const int E = in_sizes[1] / 2;
  const int Etot = E + N;
  float* out = (float*)d_out;
  (void)out_size; (void)n_in; (void)ws_size;

  // ---------------- workspace layout ----------------
  char* ws = (char*)d_ws;
  size_t off_b = 0;
  auto alloc = [&](size_t bytes) {
    void* p = ws + off_b;
    off_b += (bytes + 255) & ~(size_t)255;
    return p;
  };
  unsigned*       xl1p   = (unsigned*)alloc((size_t)N * 64 * 4);  // packed bf16 pairs
  unsigned*       xr1p   = (unsigned*)alloc((size_t)N * 64 * 4);
  unsigned*       h1b    = (unsigned*)alloc((size_t)N * 64 * 4);  // h1 as bf16 rows
  int*            bucket = (int*)alloc((size_t)(Etot + 8) * 4);
  int*            esrc   = (int*)alloc((size_t)Etot * 4);
  int*            edst   = (int*)alloc((size_t)Etot * 4);
  int*            csroff = (int*)alloc((size_t)(N + 1) * 4);
  int*            cursor = (int*)alloc((size_t)N * 4);
  int*            count  = (int*)alloc((size_t)N * 4);
  int*            perm   = (int*)alloc((size_t)N * 4);
  int*            bsum   = (int*)alloc(256 * 4);
  int*            hist2d = (int*)alloc(256 * 32 * 4);
  int*            base2d = (int*)alloc(256 * 32 * 4);
  unsigned short* WbT1   = (unsigned short*)alloc(256 * 128 * 2);
  unsigned short* WbT2   = (unsigned short*)alloc(64 * 128 * 2);

  // layer-2 packed transforms overlay the (then-dead) xl1p region
  unsigned* xl2p = xl1p;
  unsigned* xr2p = xl1p + (size_t)N * 16;

  const int nscan = (N + 255) / 256;
  const int rsz = (N + 7) / 8;
  const int nch = 256;
  const int ce = (Etot + nch - 1) / nch;
  const int eblk = (Etot + 255) / 256;
  const int cs = (N + 31) / 32;
  const int pblk = max((320 * 128 + 255) / 256, (N + 255) / 256);
  const int g1blk = (N + 63) / 64;

  // 1. weight packing + count zeroing
  hipLaunchKernelGGL(packW2_k, dim3(pblk), dim3(256), 0, stream,
                     Wl1, Wr1, Wl2, Wr2, WbT1, WbT2, count, N);

  // 2. edge conversion (+ inline detection + degree histogram)
  hipLaunchKernelGGL(convert_k, dim3(eblk), dim3(256), 0, stream,
                     ei, esrc, edst, count, E, Etot, N);

  // 3-5. scan pipeline (block-range merged with LPT perm build)
  hipLaunchKernelGGL(scanA_k, dim3(nscan + 32), dim3(256), 0, stream,
                     count, bsum, hist2d, N, nscan, cs);
  hipLaunchKernelGGL(scanB_k, dim3(2), dim3(1024), 0, stream, bsum, nscan, hist2d, base2d);
  hipLaunchKernelGGL(scanC_k, dim3(nscan + 32), dim3(256), 0, stream,
                     count, bsum, csroff, cursor, base2d, perm, N, Etot, nscan, cs);

  // 6. CSR scatter (own dispatch -> L2 locality preserved)
  hipLaunchKernelGGL(scatter_xcd_k, dim3(8 * nch), dim3(256), 0, stream,
                     esrc, edst, cursor, bucket, Etot, rsz, N, ce);

  // 7. layer-1 GEMM
  hipLaunchKernelGGL(gemm1_k, dim3(g1blk), dim3(256), 0, stream, x, WbT1, xl1p, xr1p, N);

  // 8. layer-1 aggregation
  hipLaunchKernelGGL(fused_layer1_k, dim3((N + 15) / 16), dim3(256), 0, stream,
                     xl1p, xr1p, csroff, bucket, perm, att1, b1, h1b, N);

  // 9. layer-2 GEMM (bf16 A)
  hipLaunchKernelGGL(gemm2_k, dim3(g1blk), dim3(256), 0, stream, h1b, WbT2, xl2p, xr2p, N);

  // 10. layer-2 aggregation
  hipLaunchKernelGGL(fused_layer2_k, dim3((N + 15) / 16), dim3(256), 0, stream,
                     xl2p, xr2p, csroff, bucket, perm, att2, b2, out, N);
}

// Round 19
// 204.066 us; speedup vs baseline: 1.0231x; 1.0231x over previous
//
#include <hip/hip_runtime.h>

#define NEG 0.2f

typedef __attribute__((ext_vector_type(4))) float f32x4;
typedef __attribute__((ext_vector_type(8))) short bf16x8;

// ---------- bf16 pack/unpack (RNE) ----------
__device__ __forceinline__ float blo(unsigned u) { return __uint_as_float(u << 16); }
__device__ __forceinline__ float bhi(unsigned u) { return __uint_as_float(u & 0xffff0000u); }
__device__ __forceinline__ unsigned bpack(float a, float b) {
  unsigned ua = __float_as_uint(a), ub = __float_as_uint(b);
  unsigned ra = (ua + 0x7fffu + ((ua >> 16) & 1u)) >> 16;
  unsigned rb = (ub + 0x7fffu + ((ub >> 16) & 1u)) >> 16;
  return ra | (rb << 16);
}
__device__ __forceinline__ unsigned short b16(float a) {
  unsigned ua = __float_as_uint(a);
  return (unsigned short)((ua + 0x7fffu + ((ua >> 16) & 1u)) >> 16);
}

// 16-lane xor-butterfly reduce via ds_swizzle (pattern immediate, 3 inst/stage).
__device__ __forceinline__ float red16(float t) {
  t += __int_as_float(__builtin_amdgcn_ds_swizzle(__float_as_int(t), 0x041F));  // xor 1
  t += __int_as_float(__builtin_amdgcn_ds_swizzle(__float_as_int(t), 0x081F));  // xor 2
  t += __int_as_float(__builtin_amdgcn_ds_swizzle(__float_as_int(t), 0x101F));  // xor 4
  t += __int_as_float(__builtin_amdgcn_ds_swizzle(__float_as_int(t), 0x201F));  // xor 8
  return t;
}

// ---------- dispatch 1: pack weights -> bf16 B^T AND zero count ----------
__global__ void packW2_k(const float* __restrict__ Wl1, const float* __restrict__ Wr1,
                         const float* __restrict__ Wl2, const float* __restrict__ Wr2,
                         unsigned short* __restrict__ WbT1, unsigned short* __restrict__ WbT2,
                         int* __restrict__ count, int N) {
  int i = blockIdx.x * 256 + threadIdx.x;
  if (i < N) count[i] = 0;
  if (i >= 320 * 128) return;
  int col = i >> 7, k = i & 127;
  if (col < 256) {
    float v = (col < 128) ? Wl1[(size_t)k * 128 + col] : Wr1[(size_t)k * 128 + (col - 128)];
    WbT1[i] = b16(v);
  } else {
    int c2 = col - 256;   // 0..63
    float v = (c2 < 32) ? Wl2[(size_t)k * 32 + c2] : Wr2[(size_t)k * 32 + (c2 - 32)];
    WbT2[(size_t)c2 * 128 + k] = b16(v);
  }
}

// ---------- dispatch 2: convert to packed int2 + inline width detect + degree histogram ----------
__global__ void convert_k(const void* __restrict__ ei, int2* __restrict__ epack,
                          int* __restrict__ count, int E, int Etot, int n_nodes) {
  __shared__ int is64s;
  if (threadIdx.x < 64) {   // wave 0: detect int64 vs int32 (P(false+) ~ (1/N)^64)
    const long long* e64 = (const long long*)ei;
    long long v = e64[threadIdx.x];
    bool ok = (v >= 0 && v < (long long)n_nodes);
    unsigned long long bm = __ballot(ok);
    if (threadIdx.x == 0) is64s = (bm == ~0ull) ? 1 : 0;
  }
  __syncthreads();
  int is64 = is64s;
  int e = blockIdx.x * 256 + threadIdx.x;
  if (e >= Etot) return;
  int src, dst;
  if (e >= E) { src = e - E; dst = e - E; }  // self-loops appended
  else if (is64) {
    const long long* p = (const long long*)ei;
    src = (int)p[e];
    dst = (int)p[(size_t)E + e];
  } else {
    const int* p = (const int*)ei;
    src = p[e];
    dst = p[E + e];
  }
  epack[e] = make_int2(src, dst);
  atomicAdd(&count[dst], 1);
}

// ---------- dispatch 3: scanA = per-block sums (scan1) || 32-chunk LPT degree hist ----------
__global__ void scanA_k(const int* __restrict__ count, int* __restrict__ bsum,
                        int* __restrict__ hist2d, int N, int nscan, int cs) {
  __shared__ int sh[256];
  if ((int)blockIdx.x < nscan) {
    int i = blockIdx.x * 256 + threadIdx.x;
    sh[threadIdx.x] = (i < N) ? count[i] : 0;
    __syncthreads();
    for (int o = 128; o; o >>= 1) {
      if (threadIdx.x < o) sh[threadIdx.x] += sh[threadIdx.x + o];
      __syncthreads();
    }
    if (threadIdx.x == 0) bsum[blockIdx.x] = sh[0];
  } else {
    int blk = blockIdx.x - nscan;   // 0..31
    sh[threadIdx.x] = 0;
    __syncthreads();
    int hi = min(N, (blk + 1) * cs);
    for (int i = blk * cs + threadIdx.x; i < hi; i += 256) {
      int d = count[i];
      d = d < 255 ? d : 255;
      atomicAdd(&sh[255 - d], 1);   // LDS atomic; bin 0 = highest degree
    }
    __syncthreads();
    hist2d[threadIdx.x * 32 + blk] = sh[threadIdx.x];
  }
}

// ---------- dispatch 4: scanB = top scan of bsum (block 0) || 8192-elem deg scan (block 1) ----------
__global__ void scanB_k(int* __restrict__ bsum, int nb,
                        const int* __restrict__ hist2d, int* __restrict__ base2d) {
  __shared__ int sd[1024];
  int t = threadIdx.x;
  if (blockIdx.x == 0) {
    int v = (t < nb) ? bsum[t] : 0;
    sd[t] = v;
    __syncthreads();
    for (int o = 1; o < 256; o <<= 1) {
      int x = (t >= o) ? sd[t - o] : 0;
      __syncthreads();
      sd[t] += x;
      __syncthreads();
    }
    if (t < nb) bsum[t] = sd[t] - v;
  } else {
    int v[8], s = 0;
#pragma unroll
    for (int k = 0; k < 8; ++k) { v[k] = hist2d[t * 8 + k]; s += v[k]; }
    sd[t] = s;
    __syncthreads();
    for (int o = 1; o < 1024; o <<= 1) {
      int x = (t >= o) ? sd[t - o] : 0;
      __syncthreads();
      sd[t] += x;
      __syncthreads();
    }
    int run = sd[t] - s;
#pragma unroll
    for (int k = 0; k < 8; ++k) { base2d[t * 8 + k] = run; run += v[k]; }
  }
}

// ---------- dispatch 5: scanC = csroff/cursor (scan3) || LPT perm scatter ----------
__global__ void scanC_k(const int* __restrict__ count, const int* __restrict__ bsum,
                        int* __restrict__ csroff, int* __restrict__ cursor,
                        const int* __restrict__ base2d, int* __restrict__ perm,
                        int N, int Etot, int nscan, int cs) {
  __shared__ int sh[256];
  if ((int)blockIdx.x < nscan) {
    int i = blockIdx.x * 256 + threadIdx.x;
    int v = (i < N) ? count[i] : 0;
    sh[threadIdx.x] = v;
    __syncthreads();
    for (int o = 1; o < 256; o <<= 1) {
      int t2 = (threadIdx.x >= o) ? sh[threadIdx.x - o] : 0;
      __syncthreads();
      sh[threadIdx.x] += t2;
      __syncthreads();
    }
    if (i < N) {
      int ex = bsum[blockIdx.x] + sh[threadIdx.x] - v;
      csroff[i] = ex;
      cursor[i] = ex;
    }
    if (i == 0) csroff[N] = Etot;
  } else {
    int blk = blockIdx.x - nscan;   // 0..31
    sh[threadIdx.x] = 0;
    __syncthreads();
    int hi = min(N, (blk + 1) * cs);
    for (int i = blk * cs + threadIdx.x; i < hi; i += 256) {
      int d = count[i];
      d = d < 255 ? d : 255;
      int db = 255 - d;
      int r = atomicAdd(&sh[db], 1);   // intra-bin order arbitrary; outputs unaffected
      perm[base2d[db * 32 + blk] + r] = i;
    }
  }
}

// ---------- GEMM body (device): [xl|xr](bid rows) = X @ WbT ----------
template <int NCOL, int C, int HS, bool PAIRI, bool ABF16>
__device__ __forceinline__ void gemm_body(int bid, const void* __restrict__ Xv,
                                          const unsigned short* __restrict__ WbT,
                                          unsigned* __restrict__ xl_p, unsigned* __restrict__ xr_p,
                                          int nrows) {
  constexpr int NF = NCOL / 16;
  constexpr int NPM = C / 2;
  constexpr int FPM = C / 16;
  constexpr int FPH = HS / 16;
  constexpr int POFF = HS / 32;
  const int wave = threadIdx.x >> 6;
  const int lane = threadIdx.x & 63;
  const int row0 = bid * 64 + wave * 16;
  const int rA = row0 + (lane & 15);
  const int rAc = (rA < nrows) ? rA : (nrows - 1);
  const int kA = (lane >> 4) * 8;
  const int colB = lane & 15;

  f32x4 acc[NF];
#pragma unroll
  for (int f = 0; f < NF; ++f) acc[f] = (f32x4){0.f, 0.f, 0.f, 0.f};

#pragma unroll
  for (int k0 = 0; k0 < 128; k0 += 32) {
    union { unsigned u[4]; uint4 u4; bf16x8 v; } af;
    if (ABF16) {
      const unsigned short* Xb = (const unsigned short*)Xv;
      af.u4 = *(const uint4*)&Xb[(size_t)rAc * 128 + k0 + kA];
    } else {
      const float* X = (const float*)Xv;
      const float* ax = &X[(size_t)rAc * 128 + k0 + kA];
      float4 a0 = *(const float4*)ax;
      float4 a1 = *(const float4*)(ax + 4);
      af.u[0] = bpack(a0.x, a0.y);
      af.u[1] = bpack(a0.z, a0.w);
      af.u[2] = bpack(a1.x, a1.y);
      af.u[3] = bpack(a1.z, a1.w);
    }
#pragma unroll
    for (int nf = 0; nf < NF; ++nf) {
      union { uint4 u4; bf16x8 v; } bf;
      bf.u4 = *(const uint4*)&WbT[(size_t)(nf * 16 + colB) * 128 + k0 + kA];
      acc[nf] = __builtin_amdgcn_mfma_f32_16x16x32_bf16(af.v, bf.v, acc[nf], 0, 0, 0);
    }
  }

#pragma unroll
  for (int mat = 0; mat < 2; ++mat) {
    unsigned* outp = mat ? xr_p : xl_p;
#pragma unroll
    for (int mf = 0; mf < FPM; ++mf) {
      int head = mf / FPH, hf = mf % FPH;
      if (hf >= POFF) continue;
      int f = mat * FPM + mf;
      int pair = hf * 16 + colB;
      int q = PAIRI ? (2 * pair + head) : (head * (HS / 2) + pair);
#pragma unroll
      for (int r = 0; r < 4; ++r) {
        int row = row0 + ((lane >> 4) << 2) + r;
        if (row < nrows) outp[(size_t)row * NPM + q] = bpack(acc[f][r], acc[f + POFF][r]);
      }
    }
  }
}

// ---------- dispatch 6: CSR scatter (XCD-partitioned) || layer-1 GEMM (independent) ----------
__global__ void scatter_gemm1_k(const int2* __restrict__ epack,
                                int* __restrict__ cursor, int* __restrict__ bucket,
                                int Etot, int rsz, int N, int ce, int nsc,
                                const float* __restrict__ x, const unsigned short* __restrict__ WbT1,
                                unsigned* __restrict__ xl1p, unsigned* __restrict__ xr1p) {
  if ((int)blockIdx.x < nsc) {
    int r = blockIdx.x & 7, c = blockIdx.x >> 3;
    int lo = r * rsz, hi = min(N, lo + rsz);
    int eend = min(Etot, (c + 1) * ce);
    for (int e = c * ce + threadIdx.x; e < eend; e += 256) {
      int2 sd = epack[e];
      if (sd.y >= lo && sd.y < hi) {
        int pos = atomicAdd(&cursor[sd.y], 1);
        bucket[pos] = sd.x;
      }
    }
  } else {
    gemm_body<256, 128, 64, true, false>(blockIdx.x - nsc, (const void*)x, WbT1, xl1p, xr1p, N);
  }
}

// ---------- dispatch 8: layer-2 GEMM (bf16 A) ----------
__global__ void gemm2_k(const unsigned* __restrict__ h1b, const unsigned short* __restrict__ WbT2,
                        unsigned* __restrict__ xl2p, unsigned* __restrict__ xr2p, int N) {
  gemm_body<64, 32, 32, false, true>(blockIdx.x, (const void*)h1b, WbT2, xl2p, xr2p, N);
}

// ---------- dispatch 7: layer 1 fused (16 lanes/node, LPT perm, depth-3, bf16 out) ----------
__global__ void fused_layer1_k(const unsigned* __restrict__ xl_p, const unsigned* __restrict__ xr_p,
                               const int* __restrict__ off, const int* __restrict__ bucket,
                               const int* __restrict__ perm,
                               const float* __restrict__ att, const float* __restrict__ b,
                               unsigned* __restrict__ h1b, int N) {
  int grp = threadIdx.x >> 4, sub = threadIdx.x & 15;
  int idx = blockIdx.x * 16 + grp;
  if (idx >= N) return;
  int node = perm[idx];
  const int c0 = 2 * sub, c1 = 2 * sub + 1;
  uint4 xr4 = *(const uint4*)&xr_p[(size_t)node * 64 + 4 * sub];
  float xr0 = blo(xr4.x), xr1 = bhi(xr4.x);   // h0: ch c0, c0+32
  float xr2 = blo(xr4.y), xr3 = bhi(xr4.y);   // h1: ch 64+c0, 96+c0
  float xr4f = blo(xr4.z), xr5 = bhi(xr4.z);  // h0: ch c1, c1+32
  float xr6 = blo(xr4.w), xr7 = bhi(xr4.w);   // h1: ch 64+c1, 96+c1
  float at0 = att[c0], at1 = att[c0 + 32], at2 = att[64 + c0], at3 = att[96 + c0];
  float at4 = att[c1], at5 = att[c1 + 32], at6 = att[64 + c1], at7 = att[96 + c1];

  float m0 = -INFINITY, m1 = -INFINITY, s0 = 0.f, s1 = 0.f;
  float o0 = 0.f, o1 = 0.f, o2 = 0.f, o3 = 0.f, o4 = 0.f, o5 = 0.f, o6 = 0.f, o7 = 0.f;
  int j = off[node], jend = off[node + 1];

  auto tpart = [&](uint4 v, float* vv, float& t0, float& t1) {
    vv[0] = blo(v.x); vv[1] = bhi(v.x); vv[2] = blo(v.y); vv[3] = bhi(v.y);
    vv[4] = blo(v.z); vv[5] = bhi(v.z); vv[6] = blo(v.w); vv[7] = bhi(v.w);
    float e0 = vv[0] + xr0;  e0 = fmaxf(e0, NEG * e0);
    float e1 = vv[1] + xr1;  e1 = fmaxf(e1, NEG * e1);
    float e2 = vv[2] + xr2;  e2 = fmaxf(e2, NEG * e2);
    float e3 = vv[3] + xr3;  e3 = fmaxf(e3, NEG * e3);
    float e4 = vv[4] + xr4f; e4 = fmaxf(e4, NEG * e4);
    float e5 = vv[5] + xr5;  e5 = fmaxf(e5, NEG * e5);
    float e6 = vv[6] + xr6;  e6 = fmaxf(e6, NEG * e6);
    float e7 = vv[7] + xr7;  e7 = fmaxf(e7, NEG * e7);
    t0 = fmaf(e0, at0, e1 * at1) + fmaf(e4, at4, e5 * at5);
    t1 = fmaf(e2, at2, e3 * at3) + fmaf(e6, at6, e7 * at7);
  };

  auto LD = [&](int jj, uint4& a, uint4& bq, int& cnt) {
    int i0 = bucket[jj];
    bool two = (jj + 1 < jend);
    int i1 = two ? bucket[jj + 1] : i0;
    a  = *(const uint4*)&xl_p[(size_t)i0 * 64 + 4 * sub];
    bq = *(const uint4*)&xl_p[(size_t)i1 * 64 + 4 * sub];
    cnt = two ? 2 : 1;
  };

  uint4 a0, b0q, a1, b1q, a2, b2q;
  int c0n = 0, c1n = 0, c2n = 0;
  LD(j, a0, b0q, c0n);
  bool h1v = (j + 2 < jend);
  if (h1v) LD(j + 2, a1, b1q, c1n);
  bool h2v = (j + 4 < jend);
  if (h2v) LD(j + 4, a2, b2q, c2n);

  for (;;) {
    bool h3v = (j + 6 < jend);
    uint4 na, nb;
    int ncn = 0;
    if (h3v) LD(j + 6, na, nb, ncn);   // depth-3 prefetch

    float va[8], vb[8], t0a, t1a, t0b, t1b;
    tpart(a0, va, t0a, t1a);
    tpart(b0q, vb, t0b, t1b);
    if (c0n < 2) { t0b = -1e30f; t1b = -1e30f; }

    t0a = red16(t0a); t1a = red16(t1a);
    t0b = red16(t0b); t1b = red16(t1b);

    float tm0 = fmaxf(t0a, t0b), tm1 = fmaxf(t1a, t1b);
    if (__any((tm0 > m0 + 8.f) || (tm1 > m1 + 8.f))) {
      float nm0 = fmaxf(m0, tm0), nm1 = fmaxf(m1, tm1);
      float c0r = __expf(m0 - nm0), c1r = __expf(m1 - nm1);
      s0 *= c0r; s1 *= c1r;
      o0 *= c0r; o1 *= c0r; o4 *= c0r; o5 *= c0r;
      o2 *= c1r; o3 *= c1r; o6 *= c1r; o7 *= c1r;
      m0 = nm0; m1 = nm1;
    }
    float p0a_e = __expf(t0a - m0), p1a_e = __expf(t1a - m1);
    float p0b_e = __expf(t0b - m0), p1b_e = __expf(t1b - m1);
    s0 += p0a_e + p0b_e;
    s1 += p1a_e + p1b_e;
    o0 = fmaf(p0a_e, va[0], fmaf(p0b_e, vb[0], o0));
    o1 = fmaf(p0a_e, va[1], fmaf(p0b_e, vb[1], o1));
    o4 = fmaf(p0a_e, va[4], fmaf(p0b_e, vb[4], o4));
    o5 = fmaf(p0a_e, va[5], fmaf(p0b_e, vb[5], o5));
    o2 = fmaf(p1a_e, va[2], fmaf(p1b_e, vb[2], o2));
    o3 = fmaf(p1a_e, va[3], fmaf(p1b_e, vb[3], o3));
    o6 = fmaf(p1a_e, va[6], fmaf(p1b_e, vb[6], o6));
    o7 = fmaf(p1a_e, va[7], fmaf(p1b_e, vb[7], o7));

    if (!h1v) break;
    a0 = a1; b0q = b1q; c0n = c1n;
    a1 = a2; b1q = b2q; c1n = c2n;
    h1v = h2v;
    if (h3v) { a2 = na; b2q = nb; c2n = ncn; }
    h2v = h3v;
    j += 2;
  }

  float i0 = 1.f / s0, i1 = 1.f / s1;
  auto elu = [](float r) { return r > 0.f ? r : __expf(r) - 1.f; };
  unsigned* row = h1b + (size_t)node * 64;
  float ra, rb;
  ra = elu(fmaf(o0, i0, b[c0]));       rb = elu(fmaf(o4, i0, b[c1]));
  row[sub] = bpack(ra, rb);
  ra = elu(fmaf(o1, i0, b[c0 + 32]));  rb = elu(fmaf(o5, i0, b[c1 + 32]));
  row[16 + sub] = bpack(ra, rb);
  ra = elu(fmaf(o2, i1, b[64 + c0]));  rb = elu(fmaf(o6, i1, b[64 + c1]));
  row[32 + sub] = bpack(ra, rb);
  ra = elu(fmaf(o3, i1, b[96 + c0]));  rb = elu(fmaf(o7, i1, b[96 + c1]));
  row[48 + sub] = bpack(ra, rb);
}

// ---------- dispatch 9: layer 2 fused ----------
__global__ void fused_layer2_k(const unsigned* __restrict__ xl_p, const unsigned* __restrict__ xr_p,
                               const int* __restrict__ off, const int* __restrict__ bucket,
                               const int* __restrict__ perm,
                               const float* __restrict__ att, const float* __restrict__ b,
                               float* __restrict__ out, int N) {
  int idx = blockIdx.x * 16 + (threadIdx.x >> 4);
  int lane = threadIdx.x & 15;
  if (idx >= N) return;
  int node = perm[idx];
  unsigned xru = xr_p[(size_t)node * 16 + lane];
  float xr_a = blo(xru), xr_b = bhi(xru);
  float att_a = att[lane], att_b = att[lane + 16];
  float m = -INFINITY, s = 0.f, oa = 0.f, ob = 0.f;
  int j0 = off[node], jend = off[node + 1];

  auto tpart = [&](unsigned vu, float& va, float& vb) {
    va = blo(vu); vb = bhi(vu);
    float ea = va + xr_a; ea = fmaxf(ea, NEG * ea);
    float eb = vb + xr_b; eb = fmaxf(eb, NEG * eb);
    return fmaf(ea, att_a, eb * att_b);
  };

  auto upd4 = [&](const unsigned* v, int nvalid) {
    float va0, vb0, va1, vb1, va2, vb2, va3, vb3;
    float t0 = tpart(v[0], va0, vb0);
    float t1 = tpart(v[1], va1, vb1);
    float t2 = tpart(v[2], va2, vb2);
    float t3 = tpart(v[3], va3, vb3);
    if (nvalid < 4) {
      if (nvalid <= 1) t1 = -1e30f;
      if (nvalid <= 2) t2 = -1e30f;
      t3 = -1e30f;
    }
    t0 = red16(t0); t1 = red16(t1); t2 = red16(t2); t3 = red16(t3);
    float tm = fmaxf(fmaxf(t0, t1), fmaxf(t2, t3));
    if (__any(tm > m + 8.f)) {
      float nm = fmaxf(m, tm);
      float c = __expf(m - nm);
      s *= c; oa *= c; ob *= c;
      m = nm;
    }
    float p0 = __expf(t0 - m), p1 = __expf(t1 - m);
    float p2 = __expf(t2 - m), p3 = __expf(t3 - m);
    s += (p0 + p1) + (p2 + p3);
    oa = fmaf(p0, va0, fmaf(p1, va1, fmaf(p2, va2, fmaf(p3, va3, oa))));
    ob = fmaf(p0, vb0, fmaf(p1, vb1, fmaf(p2, vb2, fmaf(p3, vb3, ob))));
  };

  unsigned cv[4], nv[4];
  int deg = jend - j0;
#pragma unroll
  for (int k = 0; k < 4; ++k) {
    int idx2 = j0 + ((k < deg) ? k : 0);
    cv[k] = xl_p[(size_t)bucket[idx2] * 16 + lane];
  }
  int j = j0;
  for (;;) {
    int jn = j + 4;
    bool more = jn < jend;
    if (more) {
      int rem = jend - jn;
#pragma unroll
      for (int k = 0; k < 4; ++k) {
        int idx2 = jn + ((k < rem) ? k : 0);
        nv[k] = xl_p[(size_t)bucket[idx2] * 16 + lane];
      }
    }
    int nvalid = jend - j; if (nvalid > 4) nvalid = 4;
    upd4(cv, nvalid);
    if (!more) break;
#pragma unroll
    for (int k = 0; k < 4; ++k) cv[k] = nv[k];
    j = jn;
  }

  float inv = 1.f / s;
  out[(size_t)node * 32 + lane]      = fmaf(oa, inv, b[lane]);
  out[(size_t)node * 32 + 16 + lane] = fmaf(ob, inv, b[lane + 16]);
}

extern "C" void kernel_launch(void* const* d_in, const int* in_sizes, int n_in,
                              void* d_out, int out_size, void* d_ws, size_t ws_size,
                              hipStream_t stream) {
  const float* x    = (const float*)d_in[0];
  const void*  ei   = d_in[1];
  const float* Wl1  = (const float*)d_in[2];
  const float* Wr1  = (const float*)d_in[3];
  const float* att1 = (const float*)d_in[4];
  const float* b1   = (const float*)d_in[5];
  const float* Wl2  = (const float*)d_in[6];
  const float* Wr2  = (const float*)d_in[7];
  const float* att2 = (const float*)d_in[8];
  const float* b2   = (const float*)d_in[9];

  const int N = in_sizes[0] / 128;
  const int E = in_sizes[1] / 2;
  const int Etot = E + N;
  float* out = (float*)d_out;
  (void)out_size; (void)n_in; (void)ws_size;

  // ---------------- workspace layout ----------------
  char* ws = (char*)d_ws;
  size_t off_b = 0;
  auto alloc = [&](size_t bytes) {
    void* p = ws + off_b;
    off_b += (bytes + 255) & ~(size_t)255;
    return p;
  };
  unsigned*       xl1p   = (unsigned*)alloc((size_t)N * 64 * 4);  // packed bf16 pairs
  unsigned*       xr1p   = (unsigned*)alloc((size_t)N * 64 * 4);
  unsigned*       h1b    = (unsigned*)alloc((size_t)N * 64 * 4);  // h1 as bf16 rows
  int*            bucket = (int*)alloc((size_t)(Etot + 8) * 4);
  int2*           epack  = (int2*)alloc((size_t)Etot * 8);
  int*            csroff = (int*)alloc((size_t)(N + 1) * 4);
  int*            cursor = (int*)alloc((size_t)N * 4);
  int*            count  = (int*)alloc((size_t)N * 4);
  int*            perm   = (int*)alloc((size_t)N * 4);
  int*            bsum   = (int*)alloc(256 * 4);
  int*            hist2d = (int*)alloc(256 * 32 * 4);
  int*            base2d = (int*)alloc(256 * 32 * 4);
  unsigned short* WbT1   = (unsigned short*)alloc(256 * 128 * 2);
  unsigned short* WbT2   = (unsigned short*)alloc(64 * 128 * 2);

  // layer-2 packed transforms overlay the (then-dead) xl1p region
  unsigned* xl2p = xl1p;
  unsigned* xr2p = xl1p + (size_t)N * 16;

  const int nscan = (N + 255) / 256;
  const int rsz = (N + 7) / 8;
  const int nch = 256;
  const int nsc = 8 * nch;
  const int ce = (Etot + nch - 1) / nch;
  const int eblk = (Etot + 255) / 256;
  const int cs = (N + 31) / 32;
  const int pblk = max((320 * 128 + 255) / 256, (N + 255) / 256);
  const int g1blk = (N + 63) / 64;

  // 1. weight packing + count zeroing
  hipLaunchKernelGGL(packW2_k, dim3(pblk), dim3(256), 0, stream,
                     Wl1, Wr1, Wl2, Wr2, WbT1, WbT2, count, N);

  // 2. edge conversion (+ inline detection + degree histogram)
  hipLaunchKernelGGL(convert_k, dim3(eblk), dim3(256), 0, stream,
                     ei, epack, count, E, Etot, N);

  // 3-5. scan pipeline (block-range merged with LPT perm build)
  hipLaunchKernelGGL(scanA_k, dim3(nscan + 32), dim3(256), 0, stream,
                     count, bsum, hist2d, N, nscan, cs);
  hipLaunchKernelGGL(scanB_k, dim3(2), dim3(1024), 0, stream, bsum, nscan, hist2d, base2d);
  hipLaunchKernelGGL(scanC_k, dim3(nscan + 32), dim3(256), 0, stream,
                     count, bsum, csroff, cursor, base2d, perm, N, Etot, nscan, cs);

  // 6. CSR scatter || layer-1 GEMM (independent work, one dispatch — R17 best config)
  hipLaunchKernelGGL(scatter_gemm1_k, dim3(nsc + g1blk), dim3(256), 0, stream,
                     epack, cursor, bucket, Etot, rsz, N, ce, nsc,
                     x, WbT1, xl1p, xr1p);

  // 7. layer-1 aggregation
  hipLaunchKernelGGL(fused_layer1_k, dim3((N + 15) / 16), dim3(256), 0, stream,
                     xl1p, xr1p, csroff, bucket, perm, att1, b1, h1b, N);

  // 8. layer-2 GEMM (bf16 A)
  hipLaunchKernelGGL(gemm2_k, dim3(g1blk), dim3(256), 0, stream, h1b, WbT2, xl2p, xr2p, N);

  // 9. layer-2 aggregation
  hipLaunchKernelGGL(fused_layer2_k, dim3((N + 15) / 16), dim3(256), 0, stream,
                     xl2p, xr2p, csroff, bucket, perm, att2, b2, out, N);
}